// Round 4
// baseline (1468.733 us; speedup 1.0000x reference)
//
#include <hip/hip_runtime.h>
#include <hip/hip_bf16.h>

#define NN  20000
#define NE  320000
#define FIN 256
#define FH  512

typedef __attribute__((ext_vector_type(8))) short bf16x8;
typedef __attribute__((ext_vector_type(4))) float f32x4;
typedef __attribute__((ext_vector_type(4))) unsigned short u16x4;
typedef __attribute__((ext_vector_type(4))) unsigned int u32x4;

static __device__ __forceinline__ unsigned short f2b(float f) {
    union { float f; unsigned int i; } v; v.f = f;
    return (unsigned short)((v.i + 0x7fffu + ((v.i >> 16) & 1u)) >> 16);
}
static __device__ __forceinline__ f32x4 mfma16(bf16x8 a, bf16x8 b, f32x4 c) {
    return __builtin_amdgcn_mfma_f32_16x16x32_bf16(a, b, c, 0, 0, 0);
}
static __device__ __forceinline__ u16x4 pack4(float a, float b, float c, float d) {
    u16x4 p;
    p[0] = f2b(a); p[1] = f2b(b); p[2] = f2b(c); p[3] = f2b(d);
    return p;
}
// 2x f32 -> packed bf16 pair (lowers to v_cvt_pk_bf16_f32)
static __device__ __forceinline__ unsigned int cvtpk(float lo, float hi) {
    union { __hip_bfloat162 h; unsigned int u; } v;
    v.h = __float22bfloat162_rn(float2{lo, hi});
    return v.u;
}
// 8x f32 -> bf16x8 via packed RNE converts
static __device__ __forceinline__ bf16x8 cvt8(f32x4 a, f32x4 b) {
    u32x4 t;
    t[0] = cvtpk(a[0], a[1]);
    t[1] = cvtpk(a[2], a[3]);
    t[2] = cvtpk(b[0], b[1]);
    t[3] = cvtpk(b[2], b[3]);
    return __builtin_bit_cast(bf16x8, t);
}

// ------------------------------------------------- all-weights transpose+cvt
__global__ void prep_weights(const float* __restrict__ We1, const float* __restrict__ We2,
                             const float* __restrict__ Wn1, const float* __restrict__ Wn2,
                             unsigned short* __restrict__ W1T, unsigned short* __restrict__ W2T,
                             unsigned short* __restrict__ Wn1T, unsigned short* __restrict__ Wn2T) {
    const int m = blockIdx.x >> 7;
    const int t = blockIdx.x & 127;
    const float* src; unsigned short* dst; int R, C;
    if      (m == 0) { src = We1; dst = W1T;  R = 256; C = 512; }
    else if (m == 1) { src = We2; dst = W2T;  R = 512; C = 256; }
    else if (m == 2) { src = Wn1; dst = Wn1T; R = 256; C = 512; }
    else             { src = Wn2; dst = Wn2T; R = 512; C = 256; }
    __shared__ unsigned short tl[32][33];
    const int tx  = threadIdx.x & 31;
    const int tyb = threadIdx.x >> 5;
    const int cb = C >> 5;
    const int bx = t % cb, by = t / cb;
    #pragma unroll
    for (int j = 0; j < 4; ++j)
        tl[tyb * 4 + j][tx] = f2b(src[(size_t)(by * 32 + tyb * 4 + j) * C + bx * 32 + tx]);
    __syncthreads();
    #pragma unroll
    for (int j = 0; j < 4; ++j)
        dst[(size_t)(bx * 32 + tyb * 4 + j) * R + by * 32 + tx] = tl[tx][tyb * 4 + j];
}

// ------------------------------------------------- sort-by-dst prep
__global__ void hist_dst(const int* __restrict__ dstI, int* __restrict__ cnt) {
    int e = blockIdx.x * 256 + threadIdx.x;
    if (e < NE) atomicAdd(&cnt[dstI[e]], 1);
}

__global__ void scan_excl(const int* __restrict__ cnt, int* __restrict__ cursor) {
    __shared__ int c[NN];          // 80 KB
    __shared__ int s[1024];
    const int t = threadIdx.x;
    for (int i = t; i < NN; i += 1024) c[i] = cnt[i];
    __syncthreads();
    const int lo = t * 20;
    const int hi = (lo + 20 < NN) ? lo + 20 : NN;
    int sum = 0;
    for (int i = lo; i < hi; ++i) sum += c[i];
    s[t] = sum;
    __syncthreads();
    for (int off = 1; off < 1024; off <<= 1) {
        int v = (t >= off) ? s[t - off] : 0;
        __syncthreads();
        s[t] += v;
        __syncthreads();
    }
    int base = (t > 0) ? s[t - 1] : 0;
    for (int i = lo; i < hi; ++i) { int cv = c[i]; c[i] = base; base += cv; }
    __syncthreads();
    for (int i = t; i < NN; i += 1024) cursor[i] = c[i];
}

__global__ void scatter_perm(const int* __restrict__ dstI,
                             int* __restrict__ cursor, int* __restrict__ perm) {
    int e = blockIdx.x * 256 + threadIdx.x;
    if (e < NE) {
        int pos = atomicAdd(&cursor[dstI[e]], 1);
        perm[pos] = e;
    }
}

// ---------------------------------------------------------------- edge MLP
// Persistent: 512 blocks x 512 threads; block handles ~10 contiguous sorted
// tiles within its XCD's chunk. L1 reads X straight from global (L2-served,
// cvt to bf16 in regs) -> no staging phase, 4 barriers/tile. Next tile's
// indices prefetched during L1 into parity-buffered LDS arrays.
__global__ void __launch_bounds__(512, 4)
gine_edge(const float* __restrict__ edge_feat,
          const float* __restrict__ node_feat,
          const int* __restrict__ srcI,
          const int* __restrict__ dstI,
          const int* __restrict__ perm,
          const unsigned short* __restrict__ W1T,   // [512,256] bf16 k-contig
          const float* __restrict__ b1,             // [512]
          const unsigned short* __restrict__ W2T,   // [256,512] bf16 k-contig
          const float* __restrict__ b2,             // [256]
          float* __restrict__ out_h)                // [NN,256] fp32 accum
{
    __shared__ union {
        unsigned short Hs[64 * 512];   // XOR-swizzled hidden (64 KB)
        float          Msg[64 * 260];  // fp32 messages, +4 pad (66.5 KB)
    } sh;
    __shared__ int snS[2][64], dnS[2][64], eS[2][64];

    const int tid  = threadIdx.x;
    const int wave = tid >> 6;       // 0..7
    const int lane = tid & 63;
    const int quad = lane >> 4;
    const int ln   = lane & 15;

    // XCD x owns sorted tiles [x*625,(x+1)*625); 64 blocks per XCD,
    // contiguous runs: first 49 blocks get 10 tiles, rest get 9.
    const int x = blockIdx.x & 7;
    const int j = blockIdx.x >> 3;               // 0..63
    const int off   = (j < 49) ? j * 10 : 490 + (j - 49) * 9;
    const int ntile = (j < 49) ? 10 : 9;
    const int t0    = x * 625 + off;

    if (tid < 64) {
        const int e = perm[t0 * 64 + tid];
        eS[0][tid] = e; snS[0][tid] = srcI[e]; dnS[0][tid] = dstI[e];
    }
    __syncthreads();

    const unsigned short* wB  = W1T + (wave * 64 + ln) * FIN + quad * 8;
    const unsigned short* w2B = W2T + (wave * 32 + ln) * FH;
    const f32x4 zero4 = {0.f, 0.f, 0.f, 0.f};

    for (int i = 0; i < ntile; ++i) {
        const int p  = i & 1;
        const int q  = p ^ 1;

        // ---- index prefetch for next tile (wave 0); consumed next iter
        int eN = 0, sN = 0, dN = 0;
        const bool pf = (tid < 64) && (i + 1 < ntile);
        if (pf) {
            eN = perm[(t0 + i + 1) * 64 + tid];
            sN = srcI[eN];
            dN = dstI[eN];
        }

        // ---- per-wave x row bases (broadcast LDS reads)
        const float* xb[4];
        #pragma unroll
        for (int et = 0; et < 4; ++et)
            xb[et] = edge_feat + (size_t)eS[p][et * 16 + ln] * FIN + quad * 8;

        // ---- layer 1 (swapped): D1[n][edge]; x direct from global
        f32x4 acc1[4][4];                          // [n-tile][edge-tile]
        #pragma unroll
        for (int nt = 0; nt < 4; ++nt)
            #pragma unroll
            for (int et = 0; et < 4; ++et) acc1[nt][et] = zero4;

        #pragma unroll
        for (int ks = 0; ks < 8; ++ks) {
            bf16x8 w[4], xf[4];
            #pragma unroll
            for (int nt = 0; nt < 4; ++nt)
                w[nt] = *(const bf16x8*)(wB + nt * 16 * FIN + ks * 32);
            #pragma unroll
            for (int et = 0; et < 4; ++et) {
                const f32x4 a = *(const f32x4*)(xb[et] + ks * 32);
                const f32x4 b = *(const f32x4*)(xb[et] + ks * 32 + 4);
                xf[et] = cvt8(a, b);
            }
            #pragma unroll
            for (int nt = 0; nt < 4; ++nt)
                #pragma unroll
                for (int et = 0; et < 4; ++et)
                    acc1[nt][et] = mfma16(w[nt], xf[et], acc1[nt][et]);
        }

        if (pf) { eS[q][tid] = eN; snS[q][tid] = sN; dnS[q][tid] = dN; }

        // ---- bias + relu -> packed bf16x4 -> swizzled Hs
        #pragma unroll
        for (int nt = 0; nt < 4; ++nt) {
            const int n0 = wave * 64 + nt * 16 + quad * 4;
            const f32x4 b4 = *(const f32x4*)(b1 + n0);
            #pragma unroll
            for (int et = 0; et < 4; ++et) {
                const int edge = et * 16 + ln;
                u16x4 pk = pack4(fmaxf(acc1[nt][et][0] + b4[0], 0.f),
                                 fmaxf(acc1[nt][et][1] + b4[1], 0.f),
                                 fmaxf(acc1[nt][et][2] + b4[2], 0.f),
                                 fmaxf(acc1[nt][et][3] + b4[3], 0.f));
                *(u16x4*)(&sh.Hs[(edge << 9) + (((n0 >> 3) ^ (edge & 7)) << 3) + (n0 & 7)]) = pk;
            }
        }
        __syncthreads();   // C: Hs complete

        // ---- layer 2 (swapped): D2[n][edge]
        f32x4 acc2[2][4];
        #pragma unroll
        for (int nt = 0; nt < 2; ++nt)
            #pragma unroll
            for (int et = 0; et < 4; ++et) acc2[nt][et] = zero4;

        #pragma unroll
        for (int ks = 0; ks < 16; ++ks) {
            const int kb = ks * 4 + quad;
            bf16x8 w[2], h[4];
            #pragma unroll
            for (int nt = 0; nt < 2; ++nt)
                w[nt] = *(const bf16x8*)(w2B + nt * 16 * FH + kb * 8);
            #pragma unroll
            for (int et = 0; et < 4; ++et) {
                const int edge = et * 16 + ln;
                h[et] = *(const bf16x8*)(&sh.Hs[(edge << 9) + ((kb ^ (edge & 7)) << 3)]);
            }
            #pragma unroll
            for (int nt = 0; nt < 2; ++nt)
                #pragma unroll
                for (int et = 0; et < 4; ++et)
                    acc2[nt][et] = mfma16(w[nt], h[et], acc2[nt][et]);
        }
        __syncthreads();   // D: Hs reads done -> Msg writable

        // ---- epilogue 1: msg = relu(node_feat[src] + E) -> Msg
        #pragma unroll
        for (int nt = 0; nt < 2; ++nt) {
            const int n0 = wave * 32 + nt * 16 + quad * 4;
            const f32x4 b4 = *(const f32x4*)(b2 + n0);
            #pragma unroll
            for (int et = 0; et < 4; ++et) {
                const int edge = et * 16 + ln;
                const int sn = snS[p][edge];
                const f32x4 nf = *(const f32x4*)(node_feat + (size_t)sn * FIN + n0);
                f32x4 m;
                #pragma unroll
                for (int r = 0; r < 4; ++r)
                    m[r] = fmaxf(nf[r] + acc2[nt][et][r] + b4[r], 0.f);
                *(f32x4*)(&sh.Msg[edge * 260 + n0]) = m;
            }
        }
        __syncthreads();   // E: Msg complete

        // ---- epilogue 2: run-length reduce over sorted dst rows (2 halves)
        {
            const int col  = tid & 255;
            const int half = tid >> 8;
            const int rA   = half * 32;
            const int dF = dnS[p][rA], dL = dnS[p][rA + 31];
            float run = sh.Msg[rA * 260 + col];
            int cur = dF;
            #pragma unroll 4
            for (int row = rA + 1; row < rA + 32; ++row) {
                const int d = dnS[p][row];
                if (d != cur) {
                    if (cur == dF || cur == dL)
                        atomicAdd(&out_h[(size_t)cur * FIN + col], run);
                    else
                        out_h[(size_t)cur * FIN + col] = run;
                    run = 0.f;
                    cur = d;
                }
                run += sh.Msg[row * 260 + col];
            }
            atomicAdd(&out_h[(size_t)cur * FIN + col], run);   // cur == dL
        }
        __syncthreads();   // F: Msg reads done -> union reusable next tile
    }
}

// ---------------------------------------------------------------- node MLP
__global__ void __launch_bounds__(512, 4)
gine_node(const float* __restrict__ node_feat,
          const float* __restrict__ out_h,
          const unsigned short* __restrict__ W1T,   // [512,256] bf16
          const float* __restrict__ b1,
          const unsigned short* __restrict__ W2T,   // [256,512] bf16
          const float* __restrict__ b2,
          const float* __restrict__ eps,
          float* __restrict__ out)
{
    __shared__ union {
        unsigned short Xs[64 * 264];
        unsigned short Hs[64 * 512];
    } sh;

    const int tid  = threadIdx.x;
    const int wave = tid >> 6;       // 0..7
    const int lane = tid & 63;
    const int quad = lane >> 4;
    const int ln   = lane & 15;
    const int n0b  = blockIdx.x * 64;
    const float epsv = 1.0f + eps[0];

    // stage x = (1+eps)*node_feat + out_h  -> bf16 LDS
    #pragma unroll
    for (int it = 0; it < 4; ++it) {
        const int chunk = tid + it * 512;
        const int row = chunk >> 5;
        const int c8  = (chunk & 31) << 3;
        const int g   = n0b + row;
        bf16x8 pack = {0, 0, 0, 0, 0, 0, 0, 0};
        if (g < NN) {
            const float* pn = node_feat + (size_t)g * FIN + c8;
            const float* ph = out_h + (size_t)g * FIN + c8;
            f32x4 n0v = *(const f32x4*)(pn);
            f32x4 n1v = *(const f32x4*)(pn + 4);
            f32x4 h0v = *(const f32x4*)(ph);
            f32x4 h1v = *(const f32x4*)(ph + 4);
            #pragma unroll
            for (int j = 0; j < 4; ++j) {
                pack[j]     = (short)f2b(epsv * n0v[j] + h0v[j]);
                pack[j + 4] = (short)f2b(epsv * n1v[j] + h1v[j]);
            }
        }
        *(bf16x8*)(&sh.Xs[row * 264 + c8]) = pack;
    }
    __syncthreads();

    // ---- layer 1 (swapped)
    f32x4 zero4 = {0.f, 0.f, 0.f, 0.f};
    f32x4 acc1[4][4];
    #pragma unroll
    for (int nt = 0; nt < 4; ++nt)
        #pragma unroll
        for (int et = 0; et < 4; ++et) acc1[nt][et] = zero4;

    const unsigned short* wB = W1T + (wave * 64 + ln) * FIN + quad * 8;
    #pragma unroll
    for (int ks = 0; ks < 8; ++ks) {
        bf16x8 w[4], xv[4];
        #pragma unroll
        for (int nt = 0; nt < 4; ++nt)
            w[nt] = *(const bf16x8*)(wB + nt * 16 * FIN + ks * 32);
        #pragma unroll
        for (int et = 0; et < 4; ++et)
            xv[et] = *(const bf16x8*)(&sh.Xs[(et * 16 + ln) * 264 + quad * 8 + ks * 32]);
        #pragma unroll
        for (int nt = 0; nt < 4; ++nt)
            #pragma unroll
            for (int et = 0; et < 4; ++et)
                acc1[nt][et] = mfma16(w[nt], xv[et], acc1[nt][et]);
    }
    __syncthreads();

    #pragma unroll
    for (int nt = 0; nt < 4; ++nt) {
        const int n0 = wave * 64 + nt * 16 + quad * 4;
        const f32x4 b4 = *(const f32x4*)(b1 + n0);
        #pragma unroll
        for (int et = 0; et < 4; ++et) {
            const int edge = et * 16 + ln;
            u16x4 pk = pack4(fmaxf(acc1[nt][et][0] + b4[0], 0.f),
                             fmaxf(acc1[nt][et][1] + b4[1], 0.f),
                             fmaxf(acc1[nt][et][2] + b4[2], 0.f),
                             fmaxf(acc1[nt][et][3] + b4[3], 0.f));
            *(u16x4*)(&sh.Hs[(edge << 9) + (((n0 >> 3) ^ (edge & 7)) << 3) + (n0 & 7)]) = pk;
        }
    }
    __syncthreads();

    // ---- layer 2 (swapped)
    f32x4 acc2[2][4];
    #pragma unroll
    for (int nt = 0; nt < 2; ++nt)
        #pragma unroll
        for (int et = 0; et < 4; ++et) acc2[nt][et] = zero4;

    const unsigned short* w2B = W2T + (wave * 32 + ln) * FH;
    #pragma unroll
    for (int ks = 0; ks < 16; ++ks) {
        const int kb = ks * 4 + quad;
        bf16x8 w[2], h[4];
        #pragma unroll
        for (int nt = 0; nt < 2; ++nt)
            w[nt] = *(const bf16x8*)(w2B + nt * 16 * FH + kb * 8);
        #pragma unroll
        for (int et = 0; et < 4; ++et) {
            const int edge = et * 16 + ln;
            h[et] = *(const bf16x8*)(&sh.Hs[(edge << 9) + ((kb ^ (edge & 7)) << 3)]);
        }
        #pragma unroll
        for (int nt = 0; nt < 2; ++nt)
            #pragma unroll
            for (int et = 0; et < 4; ++et)
                acc2[nt][et] = mfma16(w[nt], h[et], acc2[nt][et]);
    }

    // C-write: 16-B vector stores
    #pragma unroll
    for (int nt = 0; nt < 2; ++nt) {
        const int n0 = wave * 32 + nt * 16 + quad * 4;
        const f32x4 b4 = *(const f32x4*)(b2 + n0);
        #pragma unroll
        for (int et = 0; et < 4; ++et) {
            const int g = n0b + et * 16 + ln;
            if (g < NN) {
                f32x4 o;
                #pragma unroll
                for (int r = 0; r < 4; ++r)
                    o[r] = acc2[nt][et][r] + b4[r];
                *(f32x4*)(out + (size_t)g * FIN + n0) = o;
            }
        }
    }
}

// ---------------------------------------------------------------- launch
extern "C" void kernel_launch(void* const* d_in, const int* in_sizes, int n_in,
                              void* d_out, int out_size, void* d_ws, size_t ws_size,
                              hipStream_t stream) {
    const float* node_feat = (const float*)d_in[0];
    const float* edge_feat = (const float*)d_in[1];
    const int* srcI = (const int*)d_in[2];
    const int* dstI = (const int*)d_in[3];
    const float* We1 = (const float*)d_in[4];
    const float* be1 = (const float*)d_in[5];
    const float* We2 = (const float*)d_in[6];
    const float* be2 = (const float*)d_in[7];
    const float* Wn1 = (const float*)d_in[8];
    const float* bn1 = (const float*)d_in[9];
    const float* Wn2 = (const float*)d_in[10];
    const float* bn2 = (const float*)d_in[11];
    const float* eps = (const float*)d_in[12];

    char* ws = (char*)d_ws;
    float* out_h = (float*)ws;                                  // 20,480,000 B
    unsigned short* W1T  = (unsigned short*)(ws + 20480000);    // 256 KB each
    unsigned short* W2T  = W1T + 131072;
    unsigned short* Wn1T = W2T + 131072;
    unsigned short* Wn2T = Wn1T + 131072;
    int* cnt    = (int*)(ws + 20480000 + 4 * 262144);           // 80 KB
    int* cursor = cnt + NN;                                     // 80 KB
    int* perm   = cursor + NN;                                  // 1.25 MB

    hipMemsetAsync(out_h, 0, (size_t)NN * FIN * sizeof(float), stream);
    hipMemsetAsync(cnt, 0, NN * sizeof(int), stream);

    prep_weights<<<512, 256, 0, stream>>>(We1, We2, Wn1, Wn2, W1T, W2T, Wn1T, Wn2T);

    hist_dst<<<(NE + 255) / 256, 256, 0, stream>>>(dstI, cnt);
    scan_excl<<<1, 1024, 0, stream>>>(cnt, cursor);
    scatter_perm<<<(NE + 255) / 256, 256, 0, stream>>>(dstI, cursor, perm);

    gine_edge<<<512, 512, 0, stream>>>(edge_feat, node_feat, srcI, dstI,
                                       perm, W1T, be1, W2T, be2, out_h);
    gine_node<<<(NN + 63) / 64, 512, 0, stream>>>(node_feat, out_h, Wn1T, bn1,
                                                  Wn2T, bn2, eps, (float*)d_out);
}